// Round 8
// baseline (94.809 us; speedup 1.0000x reference)
//
#include <hip/hip_runtime.h>

// AxonalConnections: out[n,b,:,:] = sum over 4 incoming edges (src -> n) of
//   spikes[src,b] * masks[src] * weights[e]
// Topology: src(e) = e>>2, dst(e) = (src + (e&3) + 1) & 7
//        => edges INTO dst d are e = src*4+k with src = (d-1-k)&7, k=0..3.
//
// Lessons:
//  r3: single-pass zero-redundancy f32x2: 92 us.
//  r4: any 2nd input pass misses L3 -> HBM re-fetch, regress.
//  r5: TLP doesn't help; redundant lanes hurt.  r6: f32x4 doesn't help.
//  r7: FULL load burst + sched_barrier(0): 86 us. Limiter = loads in flight.
//
// This version keeps r7's burst but goes DST-MAJOR:
//  - acc is 8 regs (one dst at a time) instead of 64 held to the end
//  - each dst's output is stored immediately -> stores spread through compute,
//    no serial 32-store tail drain per wave
//  - w burst issued in exact consumption order (edge order of the dst loop) so
//    incremental vmcnt(N) waits cover only the 4 loads actually needed next;
//    w latency hides under the mask-prescale VALU work.
// Ideal HBM traffic: 288 MiB read + 128 MiB write (~69 us @ 6.3 TB/s).

#define HW (1024 * 1024)   // H*W pixels
#define NN 8               // nodes
#define NB 4               // batch

typedef float f32x2 __attribute__((ext_vector_type(2)));

__global__ __launch_bounds__(256, 2) void axon_kernel(
    const float* __restrict__ spikes,   // [N, B, HW]
    const float* __restrict__ masks,    // [N, HW]
    const float* __restrict__ weights,  // [E, HW]
    float* __restrict__ out)            // [N, B, HW]
{
    const int t = blockIdx.x * blockDim.x + threadIdx.x;  // 0 .. HW/2 - 1
    const int p = t * 2;                                  // float offset in a plane

    // ---- burst 1: masks + spikes (consumed first, by the prescale) ----
    f32x2 m[NN], s[NN][NB];
#pragma unroll
    for (int n = 0; n < NN; ++n)
        m[n] = *reinterpret_cast<const f32x2*>(masks + n * HW + p);
#pragma unroll
    for (int n = 0; n < NN; ++n)
#pragma unroll
        for (int b = 0; b < NB; ++b)
            s[n][b] = *reinterpret_cast<const f32x2*>(spikes + (n * NB + b) * HW + p);

    // ---- burst 2: weights, in EXACT consumption order of the dst loop ----
    f32x2 w[NN][4];   // w[d][k] = weight of edge (src=(d-1-k)&7) -> d
#pragma unroll
    for (int d = 0; d < NN; ++d)
#pragma unroll
        for (int k = 0; k < 4; ++k) {
            const int src = (d - 1 - k) & 7;
            const int e   = src * 4 + k;
            w[d][k] = *reinterpret_cast<const f32x2*>(weights + e * HW + p);
        }

    // fence: no load may be sunk below; no compute hoisted above
    __builtin_amdgcn_sched_barrier(0);

    // prescale spikes by source mask (waits only on burst 1; burst 2 in flight)
#pragma unroll
    for (int n = 0; n < NN; ++n)
#pragma unroll
        for (int b = 0; b < NB; ++b)
            s[n][b] *= m[n];

    // dst-major: 8-reg accumulator, store immediately per dst
#pragma unroll
    for (int d = 0; d < NN; ++d) {
        f32x2 acc[NB];
        {
            const int src = (d - 1) & 7;          // k = 0
#pragma unroll
            for (int b = 0; b < NB; ++b)
                acc[b] = s[src][b] * w[d][0];
        }
#pragma unroll
        for (int k = 1; k < 4; ++k) {
            const int src = (d - 1 - k) & 7;
#pragma unroll
            for (int b = 0; b < NB; ++b) {
                acc[b].x = fmaf(s[src][b].x, w[d][k].x, acc[b].x);
                acc[b].y = fmaf(s[src][b].y, w[d][k].y, acc[b].y);
            }
        }
#pragma unroll
        for (int b = 0; b < NB; ++b)
            __builtin_nontemporal_store(
                acc[b], reinterpret_cast<f32x2*>(out + (d * NB + b) * HW + p));
    }
}

extern "C" void kernel_launch(void* const* d_in, const int* in_sizes, int n_in,
                              void* d_out, int out_size, void* d_ws, size_t ws_size,
                              hipStream_t stream) {
    const float* spikes  = (const float*)d_in[0];  // [8,4,1024,1024]
    const float* masks   = (const float*)d_in[1];  // [8,1024,1024]
    const float* weights = (const float*)d_in[2];  // [32,1024,1024]
    float* out = (float*)d_out;                    // [8,4,1024,1024]

    const int threads = 256;
    const int blocks  = (HW / 2) / threads;        // 2048 blocks, 1 thread / 2 pixels
    axon_kernel<<<blocks, threads, 0, stream>>>(spikes, masks, weights, out);
}

// Round 9
// 93.217 us; speedup vs baseline: 1.0171x; 1.0171x over previous
//
#include <hip/hip_runtime.h>

// AxonalConnections: out[n,b,:,:] = sum over 4 incoming edges (src -> n) of
//   spikes[src,b] * masks[src] * weights[e]
// Topology is compile-time: src(e) = e>>2, dst(e) = (src + (e&3) + 1) & 7.
//
// Lessons:
//  r1: compiler sinks re-loadable loads -> 4x weight re-reads.
//  r3: f32x2 single-pass zero-redundancy: 92 us.
//  r4: any 2nd input pass misses L3 (streams > 256MB) -> +120MB HBM, regress.
//  r5: TLP (occ 78%) doesn't help; redundant lanes hurt.
//  r6: f32x4 doesn't help (inst count not the limiter).
//  r7: FULL 72-load burst + sched_barrier(0): 85.9 us (best). Limiter = MLP.
//  r8: stores interleaved into compute share vmcnt with loads -> over-waits,
//      regress. Stores stay in the tail.
//
// r9 = r7 + NONTEMPORAL LOADS: all 72 input loads are use-once streaming;
// the nt bit skips L1 allocation (zero reuse there), shortening the request
// path. Single-variable A/B vs r7.
// Ideal HBM traffic: 288 MiB read + 128 MiB write (~69 us @ 6.3 TB/s).

#define HW (1024 * 1024)   // H*W pixels
#define NN 8               // nodes
#define NB 4               // batch

typedef float f32x2 __attribute__((ext_vector_type(2)));

__global__ __launch_bounds__(256, 2) void axon_kernel(
    const float* __restrict__ spikes,   // [N, B, HW]
    const float* __restrict__ masks,    // [N, HW]
    const float* __restrict__ weights,  // [E, HW]
    float* __restrict__ out)            // [N, B, HW]
{
    const int t = blockIdx.x * blockDim.x + threadIdx.x;  // 0 .. HW/2 - 1
    const int p = t * 2;                                  // float offset in a plane

    // ---- one big load burst: every input byte this thread will ever touch ----
    f32x2 m[NN], s[NN][NB], w[32];
#pragma unroll
    for (int n = 0; n < NN; ++n)
        m[n] = __builtin_nontemporal_load(
            reinterpret_cast<const f32x2*>(masks + n * HW + p));
#pragma unroll
    for (int n = 0; n < NN; ++n)
#pragma unroll
        for (int b = 0; b < NB; ++b)
            s[n][b] = __builtin_nontemporal_load(
                reinterpret_cast<const f32x2*>(spikes + (n * NB + b) * HW + p));
#pragma unroll
    for (int e = 0; e < 32; ++e)
        w[e] = __builtin_nontemporal_load(
            reinterpret_cast<const f32x2*>(weights + e * HW + p));

    // fence: scheduler may not sink any of the loads above into the compute
    __builtin_amdgcn_sched_barrier(0);

    f32x2 acc[NN][NB];
#pragma unroll
    for (int n = 0; n < NN; ++n)
#pragma unroll
        for (int b = 0; b < NB; ++b) acc[n][b] = (f32x2)(0.0f);

#pragma unroll
    for (int src = 0; src < NN; ++src) {
        // pre-scale spikes by source mask (feeds all 4 outgoing edges)
#pragma unroll
        for (int b = 0; b < NB; ++b) s[src][b] *= m[src];

#pragma unroll
        for (int k = 0; k < 4; ++k) {
            const int e   = src * 4 + k;
            const int dst = (src + k + 1) & 7;
#pragma unroll
            for (int b = 0; b < NB; ++b) {
                acc[dst][b].x = fmaf(s[src][b].x, w[e].x, acc[dst][b].x);
                acc[dst][b].y = fmaf(s[src][b].y, w[e].y, acc[dst][b].y);
            }
        }
    }

    // stores stay in the tail (r8 lesson: they share vmcnt with loads)
#pragma unroll
    for (int n = 0; n < NN; ++n)
#pragma unroll
        for (int b = 0; b < NB; ++b)
            __builtin_nontemporal_store(
                acc[n][b], reinterpret_cast<f32x2*>(out + (n * NB + b) * HW + p));
}

extern "C" void kernel_launch(void* const* d_in, const int* in_sizes, int n_in,
                              void* d_out, int out_size, void* d_ws, size_t ws_size,
                              hipStream_t stream) {
    const float* spikes  = (const float*)d_in[0];  // [8,4,1024,1024]
    const float* masks   = (const float*)d_in[1];  // [8,1024,1024]
    const float* weights = (const float*)d_in[2];  // [32,1024,1024]
    float* out = (float*)d_out;                    // [8,4,1024,1024]

    const int threads = 256;
    const int blocks  = (HW / 2) / threads;        // 2048 blocks, 1 thread / 2 pixels
    axon_kernel<<<blocks, threads, 0, stream>>>(spikes, masks, weights, out);
}